// Round 5
// baseline (660.445 us; speedup 1.0000x reference)
//
#include <hip/hip_runtime.h>
#include <stdint.h>

// Problem: ComplexDepthwiseBatchNorm  N=16384, C=8, F=257
// Layout: x[N][C*F] row-major; NCOLS = 2056 columns per row.
// Dtype of x / W / out is detected ON DEVICE (bf16 vs fp32) — see detect_kernel.
#define NROWS   16384
#define NCOLS   2056
#define NG      257            // groups of 8 bf16 (one uint4) per row
#define NQ      514            // groups of 4 fp32 (one float4) per row
#define EPSV    1e-6f
#define DELTA_MAX 1e8f
#define NSUM    (5*NCOLS)      // 10280 sum slots (5 stats x 2056 cols)
#define T8TOT   (NROWS*NG)     // 4,210,688 uint4 per bf16 tensor
#define T4TOT   (NROWS*NQ)     // 8,421,376 float4 per fp32 tensor

typedef float    f32x4v __attribute__((ext_vector_type(4)));
typedef float    f32x8v __attribute__((ext_vector_type(8)));
typedef uint32_t u32x4v __attribute__((ext_vector_type(4)));

__device__ __forceinline__ float bf_lo(uint32_t u) {
    return __builtin_bit_cast(float, u << 16);
}
__device__ __forceinline__ float bf_hi(uint32_t u) {
    return __builtin_bit_cast(float, u & 0xffff0000u);
}
__device__ __forceinline__ float bf1(uint16_t u) {
    return __builtin_bit_cast(float, (uint32_t)u << 16);
}
// round-to-nearest-even bf16 pair pack: lo -> bits[15:0], hi -> bits[31:16]
__device__ __forceinline__ uint32_t bf16pair(float lo, float hi) {
    uint32_t ul = __builtin_bit_cast(uint32_t, lo);
    uint32_t uh = __builtin_bit_cast(uint32_t, hi);
    ul = (ul + 0x7fffu + ((ul >> 16) & 1u)) >> 16;
    uh = (uh + 0x7fffu + ((uh >> 16) & 1u)) & 0xffff0000u;
    return ul | uh;
}

// ---------------- Pass 0: dtype detection ----------------
// flags[0]=1 iff x is fp32; flags[1]=1 iff W/B are fp32.
__global__ __launch_bounds__(512) void detect_kernel(
    const uint32_t* __restrict__ xr_u, const uint32_t* __restrict__ wrr_u,
    int* __restrict__ flags)
{
    __shared__ int cnt[2];
    if (threadIdx.x < 2) cnt[threadIdx.x] = 0;
    __syncthreads();
    const int part = threadIdx.x >> 8;                    // 0: x, 1: Wrr
    const uint32_t u = part ? wrr_u[threadIdx.x & 255] : xr_u[threadIdx.x & 255];
    const uint32_t e = (u >> 7) & 0xFFu;
    const int ok = (e >= 100u && e <= 131u) ? 1 : 0;
    atomicAdd(&cnt[part], ok);
    __syncthreads();
    if (threadIdx.x == 0) {
        flags[0] = (cnt[0] < 128) ? 1 : 0;
        flags[1] = (cnt[1] < 128) ? 1 : 0;
    }
}

// ---------------- Pass 1: per-column sums (flat stream, REGISTER accums) ----
// grid NB x block 256, TT = NB*256, NB in {514, 257} (TT | T8TOT and T4TOT,
// and TT ≡ 0 mod 257/514 so each thread's column set is FIXED across iters).
// KEY FIX vs rounds 0-4: accumulators are NAMED ext-vector registers, not a
// float[40] array. Round 0's stats reported VGPR_Count=44 with >=55 live
// values -> the acc array lived in SCRATCH; every inner-loop += was a
// scratch ld+st (~10x traffic amplification, L2-backed so invisible in
// FETCH/WRITE_SIZE). That, not the access pattern, was the ~135 us / ~1 TB/s
// cap (tile-stationary and flat-stream both measured the same). ext-vector
// elements with compile-time subscripts are guaranteed VGPRs; launch_bounds
// min-waves=1 lifts the allocator cap (round 4's (1024,8) forced <=64 VGPRs).
// Block combine: 256 consecutive tids mod 257 are DISTINCT u4-columns ->
// plain LDS scatter (no atomics, no phases), then NT-dump 41 KB partials.
__global__ __launch_bounds__(256, 1) void stats_kernel(
    const void* __restrict__ xr_p, const void* __restrict__ xi_p,
    const int* __restrict__ flags, float* __restrict__ partials,
    int TT, int nit8, int nit4)
{
    __shared__ float lds[NSUM];
    const int t = threadIdx.x;
    const int tid = blockIdx.x * 256 + t;
    for (int i = t; i < NSUM; i += 256) lds[i] = 0.f;
    __syncthreads();                    // zero visible before any scatter

    if (!flags[0]) {
        // -------- bf16: 8 fixed columns, 5 x f32x8 register accumulators ----
        f32x8v sr  = {0.f,0.f,0.f,0.f,0.f,0.f,0.f,0.f};
        f32x8v si  = sr, srr = sr, sri = sr, sii = sr;
        const uint4* __restrict__ xr4 = (const uint4*)xr_p;
        const uint4* __restrict__ xi4 = (const uint4*)xi_p;
        for (int k = 0; k < nit8; ++k) {
            const size_t g = (size_t)tid + (size_t)k * TT;
            const uint4 a = xr4[g];
            const uint4 b = xi4[g];
            const uint32_t au[4] = {a.x, a.y, a.z, a.w};
            const uint32_t bu[4] = {b.x, b.y, b.z, b.w};
            #pragma unroll
            for (int j = 0; j < 4; ++j) {
                const float r0 = bf_lo(au[j]), r1 = bf_hi(au[j]);
                const float i0 = bf_lo(bu[j]), i1 = bf_hi(bu[j]);
                sr [2*j]   += r0;       si [2*j]   += i0;
                srr[2*j]   += r0*r0;    sri[2*j]   += r0*i0;    sii[2*j]   += i0*i0;
                sr [2*j+1] += r1;       si [2*j+1] += i1;
                srr[2*j+1] += r1*r1;    sri[2*j+1] += r1*i1;    sii[2*j+1] += i1*i1;
            }
        }
        const int c = tid % NG;         // fixed u4-column; distinct per thread
        #pragma unroll
        for (int j = 0; j < 8; ++j) {
            lds[0*NCOLS + c*8 + j] = sr [j];
            lds[1*NCOLS + c*8 + j] = si [j];
            lds[2*NCOLS + c*8 + j] = srr[j];
            lds[3*NCOLS + c*8 + j] = sri[j];
            lds[4*NCOLS + c*8 + j] = sii[j];
        }
    } else {
        // -------- fp32: 4 fixed columns, 5 x f32x4 register accumulators ----
        f32x4v sr  = {0.f,0.f,0.f,0.f};
        f32x4v si  = sr, srr = sr, sri = sr, sii = sr;
        const float4* __restrict__ xr4 = (const float4*)xr_p;
        const float4* __restrict__ xi4 = (const float4*)xi_p;
        for (int k = 0; k < nit4; ++k) {
            const size_t g = (size_t)tid + (size_t)k * TT;
            const float4 a = xr4[g];
            const float4 b = xi4[g];
            const float xr[4] = {a.x, a.y, a.z, a.w};
            const float xi[4] = {b.x, b.y, b.z, b.w};
            #pragma unroll
            for (int j = 0; j < 4; ++j) {
                sr [j] += xr[j];        si [j] += xi[j];
                srr[j] += xr[j]*xr[j];  sri[j] += xr[j]*xi[j];  sii[j] += xi[j]*xi[j];
            }
        }
        const int cq = tid % NQ;        // fixed f4-group; distinct per thread
        #pragma unroll
        for (int j = 0; j < 4; ++j) {
            lds[0*NCOLS + cq*4 + j] = sr [j];
            lds[1*NCOLS + cq*4 + j] = si [j];
            lds[2*NCOLS + cq*4 + j] = srr[j];
            lds[3*NCOLS + cq*4 + j] = sri[j];
            lds[4*NCOLS + cq*4 + j] = sii[j];
        }
    }

    __syncthreads();
    // NT-store this block's partials (read once by reduce; keep x in L3)
    float* __restrict__ dst = partials + (size_t)blockIdx.x * NSUM;
    for (int i = t; i < NSUM; i += 256)
        __builtin_nontemporal_store(lds[i], dst + i);
}

// ---------------- Pass 1b+2 fused: reduce partials -> coefficients ----------
// grid 33 x block 256 = 64 cols x 4 block-lanes. For fixed (stat, b), 64
// threads read 64 consecutive floats (256 B contiguous). Then 4-lane LDS
// combine and the 2x2 inverse-sqrt + affine fold, all in one kernel.
__global__ __launch_bounds__(256) void reduce_coef_kernel(
    const float* __restrict__ partials,
    const void* __restrict__ Wrr_p, const void* __restrict__ Wri_p,
    const void* __restrict__ Wii_p, const void* __restrict__ Br_p,
    const void* __restrict__ Bi_p,
    const int* __restrict__ flags, float* __restrict__ coef, int NB)
{
    const int col = blockIdx.x * 64 + (threadIdx.x & 63);
    const int bl  = threadIdx.x >> 6;
    float a0 = 0.f, a1 = 0.f, a2 = 0.f, a3 = 0.f, a4 = 0.f;
    if (col < NCOLS) {
        for (int b = bl; b < NB; b += 4) {
            const float* __restrict__ p = partials + (size_t)b * NSUM + col;
            a0 += p[0*NCOLS]; a1 += p[1*NCOLS]; a2 += p[2*NCOLS];
            a3 += p[3*NCOLS]; a4 += p[4*NCOLS];
        }
    }
    __shared__ float red[5][256];
    red[0][threadIdx.x] = a0; red[1][threadIdx.x] = a1; red[2][threadIdx.x] = a2;
    red[3][threadIdx.x] = a3; red[4][threadIdx.x] = a4;
    __syncthreads();
    if (threadIdx.x < 64 && col < NCOLS) {
        const int j = col;
        const int u = threadIdx.x;
        const float S0 = red[0][u] + red[0][u+64] + red[0][u+128] + red[0][u+192];
        const float S1 = red[1][u] + red[1][u+64] + red[1][u+128] + red[1][u+192];
        const float S2 = red[2][u] + red[2][u+64] + red[2][u+128] + red[2][u+192];
        const float S3 = red[3][u] + red[3][u+64] + red[3][u+128] + red[3][u+192];
        const float S4 = red[4][u] + red[4][u+64] + red[4][u+128] + red[4][u+192];

        const float invN = 1.0f / (float)NROWS;
        const float Mr  = S0 * invN;
        const float Mi  = S1 * invN;
        const float Vrr = S2 * invN - Mr * Mr;
        const float Vri = S3 * invN - Mr * Mi;
        const float Vii = S4 * invN - Mi * Mi;
        const float tau   = Vrr + Vii;
        const float delta = fminf(fmaxf(Vrr * Vii - Vri * Vri, EPSV), DELTA_MAX);
        const float s   = sqrtf(delta);
        const float t   = sqrtf(tau + 2.0f * s);
        const float rst = 1.0f / (s * t);
        const float Urr = (s + Vii) * rst;
        const float Uii = (s + Vrr) * rst;
        const float Uri = -Vri * rst;

        float wrr, wri, wii, br, bi;
        if (flags[1]) {
            wrr = ((const float*)Wrr_p)[j];  wri = ((const float*)Wri_p)[j];
            wii = ((const float*)Wii_p)[j];
            br  = ((const float*)Br_p)[j];   bi  = ((const float*)Bi_p)[j];
        } else {
            wrr = bf1(((const uint16_t*)Wrr_p)[j]);  wri = bf1(((const uint16_t*)Wri_p)[j]);
            wii = bf1(((const uint16_t*)Wii_p)[j]);
            br  = bf1(((const uint16_t*)Br_p)[j]);   bi  = bf1(((const uint16_t*)Bi_p)[j]);
        }
        const float Zrr = wrr * Urr + wri * Uri;
        const float Zri = wrr * Uri + wri * Uii;
        const float Zir = wri * Urr + wii * Uri;
        const float Zii = wri * Uri + wii * Uii;
        coef[0*NCOLS+j] = Zrr;
        coef[1*NCOLS+j] = Zri;
        coef[2*NCOLS+j] = Zir;
        coef[3*NCOLS+j] = Zii;
        coef[4*NCOLS+j] = br - Zrr * Mr - Zri * Mi;
        coef[5*NCOLS+j] = bi - Zir * Mr - Zii * Mi;
    }
}

// ---------------- Pass 3: apply (column-stationary, coeffs in REGISTERS) ----
// grid 2056 x block 256 => T = 526336 = 2048*257 (bijection tid->(r0,c)).
// Flat-contiguous stream; NT stores (NT measured ~17 us faster than plain
// across rounds 1/3, and keeps x L3-resident). Z coefficients held as named
// f32x8 ext-vectors (same scratch insurance as stats). coef rows are 32 B
// aligned (2056*4 and c*8*4 both multiples of 32) -> single 32 B loads.
__global__ __launch_bounds__(256) void apply_kernel(
    const void* __restrict__ xr_p, const void* __restrict__ xi_p,
    const float* __restrict__ coef, const int* __restrict__ flags,
    void* __restrict__ out_p)
{
    const int tid = blockIdx.x * 256 + threadIdx.x;
    const int c  = tid % NG;
    const int r0 = tid / NG;            // [0,2048)
    const int col = c * 8;

    const f32x8v zrr = *(const f32x8v*)(coef + 0*NCOLS + col);
    const f32x8v zri = *(const f32x8v*)(coef + 1*NCOLS + col);
    const f32x8v zir = *(const f32x8v*)(coef + 2*NCOLS + col);
    const f32x8v zii = *(const f32x8v*)(coef + 3*NCOLS + col);
    const f32x8v cr  = *(const f32x8v*)(coef + 4*NCOLS + col);
    const f32x8v ci  = *(const f32x8v*)(coef + 5*NCOLS + col);

    if (flags[0]) {
        // -------- fp32 path --------
        const float4* xr4 = (const float4*)xr_p;
        const float4* xi4 = (const float4*)xi_p;
        f32x4v* yr4 = (f32x4v*)out_p;
        f32x4v* yi4 = yr4 + (size_t)NROWS * NQ;     // yi after N*C*F floats
        #pragma unroll 2
        for (int k = 0; k < 8; ++k) {
            const size_t g = (size_t)(r0 + (k << 11)) * NQ + 2 * c;
            const float4 a0 = xr4[g], a1 = xr4[g + 1];
            const float4 b0 = xi4[g], b1 = xi4[g + 1];
            f32x8v xv, yv;
            xv[0]=a0.x; xv[1]=a0.y; xv[2]=a0.z; xv[3]=a0.w;
            xv[4]=a1.x; xv[5]=a1.y; xv[6]=a1.z; xv[7]=a1.w;
            yv[0]=b0.x; yv[1]=b0.y; yv[2]=b0.z; yv[3]=b0.w;
            yv[4]=b1.x; yv[5]=b1.y; yv[6]=b1.z; yv[7]=b1.w;
            const f32x8v yr = zrr*xv + zri*yv + cr;
            const f32x8v yi = zir*xv + zii*yv + ci;
            const f32x4v s0 = {yr[0], yr[1], yr[2], yr[3]};
            const f32x4v s1 = {yr[4], yr[5], yr[6], yr[7]};
            const f32x4v t0 = {yi[0], yi[1], yi[2], yi[3]};
            const f32x4v t1 = {yi[4], yi[5], yi[6], yi[7]};
            __builtin_nontemporal_store(s0, yr4 + g);
            __builtin_nontemporal_store(s1, yr4 + g + 1);
            __builtin_nontemporal_store(t0, yi4 + g);
            __builtin_nontemporal_store(t1, yi4 + g + 1);
        }
    } else {
        // -------- bf16 path --------
        const uint4* xr4 = (const uint4*)xr_p;
        const uint4* xi4 = (const uint4*)xi_p;
        u32x4v* yr4 = (u32x4v*)out_p;
        u32x4v* yi4 = yr4 + (size_t)NROWS * NG;     // yi after N*C*F bf16
        #pragma unroll 2
        for (int k = 0; k < 8; ++k) {
            const size_t g = (size_t)(r0 + (k << 11)) * NG + c;
            const uint4 a = xr4[g];
            const uint4 b = xi4[g];
            const uint32_t au[4] = {a.x, a.y, a.z, a.w};
            const uint32_t bu[4] = {b.x, b.y, b.z, b.w};
            f32x8v xv, yv;
            #pragma unroll
            for (int j = 0; j < 4; ++j) {
                xv[2*j] = bf_lo(au[j]);  xv[2*j+1] = bf_hi(au[j]);
                yv[2*j] = bf_lo(bu[j]);  yv[2*j+1] = bf_hi(bu[j]);
            }
            const f32x8v yr = zrr*xv + zri*yv + cr;
            const f32x8v yi = zir*xv + zii*yv + ci;
            u32x4v o, p;
            #pragma unroll
            for (int j = 0; j < 4; ++j) {
                o[j] = bf16pair(yr[2*j], yr[2*j+1]);
                p[j] = bf16pair(yi[2*j], yi[2*j+1]);
            }
            __builtin_nontemporal_store(o, yr4 + g);
            __builtin_nontemporal_store(p, yi4 + g);
        }
    }
}

extern "C" void kernel_launch(void* const* d_in, const int* in_sizes, int n_in,
                              void* d_out, int out_size, void* d_ws, size_t ws_size,
                              hipStream_t stream)
{
    const void* xr_p = d_in[0];
    const void* xi_p = d_in[1];
    const void* Wrr  = d_in[2];
    const void* Wri  = d_in[3];
    const void* Wii  = d_in[4];
    const void* Br   = d_in[5];
    const void* Bi   = d_in[6];

    float* coef  = (float*)d_ws;                 // 6 * 2056 f32
    int*   flags = (int*)(coef + 6 * NCOLS);     // 2 ints (pad to 16)
    float* partials = (float*)(flags + 16);      // NB * NSUM f32

    // NB*256 must divide T8TOT and T4TOT (and be ≡0 mod 514): NB in {514, 257}
    const size_t base_bytes = (size_t)(6 * NCOLS + 16) * 4;
    int NB = 514;
    if (base_bytes + (size_t)NB * NSUM * 4 > ws_size) NB = 257;
    const int TT   = NB * 256;
    const int nit8 = T8TOT / TT;     // 32 (NB=514) or 64 (NB=257), exact
    const int nit4 = T4TOT / TT;     // 64 or 128, exact

    detect_kernel<<<1, 512, 0, stream>>>((const uint32_t*)xr_p, (const uint32_t*)Wrr, flags);
    stats_kernel<<<NB, 256, 0, stream>>>(xr_p, xi_p, flags, partials, TT, nit8, nit4);
    reduce_coef_kernel<<<33, 256, 0, stream>>>(partials, Wrr, Wri, Wii, Br, Bi, flags, coef, NB);
    apply_kernel<<<2056, 256, 0, stream>>>(xr_p, xi_p, coef, flags, d_out);
}

// Round 7
// 547.553 us; speedup vs baseline: 1.2062x; 1.2062x over previous
//
#include <hip/hip_runtime.h>
#include <stdint.h>

// Problem: ComplexDepthwiseBatchNorm  N=16384, C=8, F=257
// Layout: x[N][C*F] row-major; NCOLS = 2056 columns per row.
// Dtype of x / W / out is detected ON DEVICE (bf16 vs fp32) — see detect_kernel.
#define NROWS   16384
#define NCOLS   2056
#define NG      257          // groups of 8 elements per row (2056/8)
#define EPSV    1e-6f
#define DELTA_MAX 1e8f
#define SR      64           // row slices for stats (NROWS/SR = 256 rows/slice)

typedef float    f32x4v __attribute__((ext_vector_type(4)));
typedef float    f32x8v __attribute__((ext_vector_type(8)));
typedef uint32_t u32x4v __attribute__((ext_vector_type(4)));

__device__ __forceinline__ float bf_lo(uint32_t u) {
    return __builtin_bit_cast(float, u << 16);
}
__device__ __forceinline__ float bf_hi(uint32_t u) {
    return __builtin_bit_cast(float, u & 0xffff0000u);
}
__device__ __forceinline__ float bf1(uint16_t u) {
    return __builtin_bit_cast(float, (uint32_t)u << 16);
}
// round-to-nearest-even bf16 pair pack: lo -> bits[15:0], hi -> bits[31:16]
__device__ __forceinline__ uint32_t bf16pair(float lo, float hi) {
    uint32_t ul = __builtin_bit_cast(uint32_t, lo);
    uint32_t uh = __builtin_bit_cast(uint32_t, hi);
    ul = (ul + 0x7fffu + ((ul >> 16) & 1u)) >> 16;
    uh = (uh + 0x7fffu + ((uh >> 16) & 1u)) & 0xffff0000u;
    return ul | uh;
}

// ---------------- Pass 0: dtype detection ----------------
// flags[0]=1 iff x is fp32; flags[1]=1 iff W/B are fp32.
__global__ __launch_bounds__(512) void detect_kernel(
    const uint32_t* __restrict__ xr_u, const uint32_t* __restrict__ wrr_u,
    int* __restrict__ flags)
{
    __shared__ int cnt[2];
    if (threadIdx.x < 2) cnt[threadIdx.x] = 0;
    __syncthreads();
    const int part = threadIdx.x >> 8;                    // 0: x, 1: Wrr
    const uint32_t u = part ? wrr_u[threadIdx.x & 255] : xr_u[threadIdx.x & 255];
    const uint32_t e = (u >> 7) & 0xFFu;
    const int ok = (e >= 100u && e <= 131u) ? 1 : 0;
    atomicAdd(&cnt[part], ok);
    __syncthreads();
    if (threadIdx.x == 0) {
        flags[0] = (cnt[0] < 128) ? 1 : 0;
        flags[1] = (cnt[1] < 128) ? 1 : 0;
    }
}

// ---------------- Pass 1: per-column sums (tile-stationary) ----------------
// Structure IDENTICAL to the 533 us round-1-bench config (grid dim3(SR,33),
// block 256; ct<32: group = 8ct+(t&7), row-lane = t>>3, 8 rows each;
// shfl_xor over lane bits 3..5 -> LDS cross-wave combine -> 320 atomics).
// ONE change: accumulators are 5 NAMED f32x8 ext-vectors instead of
// float acc[40]. Round 0's counter showed VGPR_Count=44 with >=55 live values
// -> the array lived in SCRATCH; every inner-loop += was a buffer ld+add+st
// (~10x L1/L2 traffic, invisible in FETCH/WRITE_SIZE) — the ~1 TB/s cap all
// spilling stats variants shared. ext-vector elements with compile-time
// subscripts are guaranteed VGPRs. __launch_bounds__(256,4) caps VGPR at 128
// (fits 40 accums + pipelined loads; >=16 waves/CU) — round 5's (256,1)
// removed the cap entirely and is the suspected occupancy collapse.
__global__ __launch_bounds__(256, 4) void stats_kernel(
    const void* __restrict__ xr_p, const void* __restrict__ xi_p,
    const int* __restrict__ flags, float* __restrict__ sums)
{
    const int rs = blockIdx.x;          // 0..SR-1
    const int ct = blockIdx.y;          // 0..32
    const int t  = threadIdx.x;
    const int rbase = rs * (NROWS / SR);   // 256 rows per slice

    f32x8v sr  = {0.f,0.f,0.f,0.f,0.f,0.f,0.f,0.f};
    f32x8v si  = sr, srr = sr, sri = sr, sii = sr;

    const bool isfp32 = (flags[0] != 0);

    if (ct < 32) {
        const int grp = ct * 8 + (t & 7);
        const int rl  = t >> 3;             // 0..31
        if (!isfp32) {
            const uint4* xr4 = (const uint4*)xr_p;
            const uint4* xi4 = (const uint4*)xi_p;
            #pragma unroll 2
            for (int k = 0; k < 8; ++k) {
                const size_t g = (size_t)(rbase + rl + 32*k) * NG + grp;
                const uint4 a = xr4[g];
                const uint4 b = xi4[g];
                const uint32_t au[4] = {a.x, a.y, a.z, a.w};
                const uint32_t bu[4] = {b.x, b.y, b.z, b.w};
                #pragma unroll
                for (int j = 0; j < 4; ++j) {
                    const float r0 = bf_lo(au[j]), r1 = bf_hi(au[j]);
                    const float i0 = bf_lo(bu[j]), i1 = bf_hi(bu[j]);
                    sr [2*j]   += r0;       si [2*j]   += i0;
                    srr[2*j]   += r0*r0;    sri[2*j]   += r0*i0;    sii[2*j]   += i0*i0;
                    sr [2*j+1] += r1;       si [2*j+1] += i1;
                    srr[2*j+1] += r1*r1;    sri[2*j+1] += r1*i1;    sii[2*j+1] += i1*i1;
                }
            }
        } else {
            const float4* xr4 = (const float4*)xr_p;
            const float4* xi4 = (const float4*)xi_p;
            #pragma unroll 2
            for (int k = 0; k < 8; ++k) {
                const size_t g = (size_t)(rbase + rl + 32*k) * 514 + 2*grp;
                const float4 a0 = xr4[g], a1 = xr4[g + 1];
                const float4 b0 = xi4[g], b1 = xi4[g + 1];
                const float xrv[8] = {a0.x,a0.y,a0.z,a0.w,a1.x,a1.y,a1.z,a1.w};
                const float xiv[8] = {b0.x,b0.y,b0.z,b0.w,b1.x,b1.y,b1.z,b1.w};
                #pragma unroll
                for (int j = 0; j < 8; ++j) {
                    sr [j] += xrv[j];        si [j] += xiv[j];
                    srr[j] += xrv[j]*xrv[j]; sri[j] += xrv[j]*xiv[j];
                    sii[j] += xiv[j]*xiv[j];
                }
            }
        }
        // reduce over the 8 row-lanes sharing this group (lane bits 3..5)
        #pragma unroll
        for (int m = 8; m <= 32; m <<= 1) {
            #pragma unroll
            for (int e = 0; e < 8; ++e) {
                sr [e] += __shfl_xor(sr [e], m, 64);
                si [e] += __shfl_xor(si [e], m, 64);
                srr[e] += __shfl_xor(srr[e], m, 64);
                sri[e] += __shfl_xor(sri[e], m, 64);
                sii[e] += __shfl_xor(sii[e], m, 64);
            }
        }
    } else {
        // leftover group 256 (columns 2048..2055): one row per thread
        if (!isfp32) {
            const uint4* xr4 = (const uint4*)xr_p;
            const uint4* xi4 = (const uint4*)xi_p;
            const size_t g = (size_t)(rbase + t) * NG + 256;
            const uint4 a = xr4[g];
            const uint4 b = xi4[g];
            const uint32_t au[4] = {a.x, a.y, a.z, a.w};
            const uint32_t bu[4] = {b.x, b.y, b.z, b.w};
            #pragma unroll
            for (int j = 0; j < 4; ++j) {
                const float r0 = bf_lo(au[j]), r1 = bf_hi(au[j]);
                const float i0 = bf_lo(bu[j]), i1 = bf_hi(bu[j]);
                sr [2*j]   += r0;       si [2*j]   += i0;
                srr[2*j]   += r0*r0;    sri[2*j]   += r0*i0;    sii[2*j]   += i0*i0;
                sr [2*j+1] += r1;       si [2*j+1] += i1;
                srr[2*j+1] += r1*r1;    sri[2*j+1] += r1*i1;    sii[2*j+1] += i1*i1;
            }
        } else {
            const float4* xr4 = (const float4*)xr_p;
            const float4* xi4 = (const float4*)xi_p;
            const size_t g = (size_t)(rbase + t) * 514 + 512;
            const float4 a0 = xr4[g], a1 = xr4[g + 1];
            const float4 b0 = xi4[g], b1 = xi4[g + 1];
            const float xrv[8] = {a0.x,a0.y,a0.z,a0.w,a1.x,a1.y,a1.z,a1.w};
            const float xiv[8] = {b0.x,b0.y,b0.z,b0.w,b1.x,b1.y,b1.z,b1.w};
            #pragma unroll
            for (int j = 0; j < 8; ++j) {
                sr [j] += xrv[j];        si [j] += xiv[j];
                srr[j] += xrv[j]*xrv[j]; sri[j] += xrv[j]*xiv[j];
                sii[j] += xiv[j]*xiv[j];
            }
        }
        // full 64-lane reduction
        #pragma unroll
        for (int m = 1; m <= 32; m <<= 1) {
            #pragma unroll
            for (int e = 0; e < 8; ++e) {
                sr [e] += __shfl_xor(sr [e], m, 64);
                si [e] += __shfl_xor(si [e], m, 64);
                srr[e] += __shfl_xor(srr[e], m, 64);
                sri[e] += __shfl_xor(sri[e], m, 64);
                sii[e] += __shfl_xor(sii[e], m, 64);
            }
        }
    }

    // cross-wave combine: per-wave representatives -> LDS -> sum 4 -> atomic
    __shared__ float red[4][320];
    const int wv = t >> 6, ln = t & 63;
    if (ct < 32) {
        if (ln < 8) {
            #pragma unroll
            for (int e = 0; e < 8; ++e) {
                red[wv][ln*40 + 0*8 + e] = sr [e];
                red[wv][ln*40 + 1*8 + e] = si [e];
                red[wv][ln*40 + 2*8 + e] = srr[e];
                red[wv][ln*40 + 3*8 + e] = sri[e];
                red[wv][ln*40 + 4*8 + e] = sii[e];
            }
        }
    } else {
        if (ln == 0) {
            #pragma unroll
            for (int e = 0; e < 8; ++e) {
                red[wv][0*8 + e] = sr [e];
                red[wv][1*8 + e] = si [e];
                red[wv][2*8 + e] = srr[e];
                red[wv][3*8 + e] = sri[e];
                red[wv][4*8 + e] = sii[e];
            }
        }
    }
    __syncthreads();
    const int nvals = (ct < 32) ? 320 : 40;
    for (int idx = t; idx < nvals; idx += 256) {
        const float v = red[0][idx] + red[1][idx] + red[2][idx] + red[3][idx];
        const int gi  = idx / 40;
        const int j   = idx - gi * 40;          // stat*8 + colj
        const int col = (ct * 8 + gi) * 8 + (j & 7);
        atomicAdd(&sums[(j >> 3) * NCOLS + col], v);
    }
}

// ---------------- Pass 2: sums -> per-column coefficients ----------------
__global__ __launch_bounds__(256) void coef_kernel(
    const float* __restrict__ sums,
    const void* __restrict__ Wrr_p, const void* __restrict__ Wri_p,
    const void* __restrict__ Wii_p, const void* __restrict__ Br_p,
    const void* __restrict__ Bi_p,
    const int* __restrict__ flags, float* __restrict__ coef)
{
    const int j = blockIdx.x * 256 + threadIdx.x;
    if (j >= NCOLS) return;
    const float invN = 1.0f / (float)NROWS;
    const float Mr  = sums[0*NCOLS+j] * invN;
    const float Mi  = sums[1*NCOLS+j] * invN;
    const float Vrr = sums[2*NCOLS+j] * invN - Mr * Mr;
    const float Vri = sums[3*NCOLS+j] * invN - Mr * Mi;
    const float Vii = sums[4*NCOLS+j] * invN - Mi * Mi;
    const float tau   = Vrr + Vii;
    const float delta = fminf(fmaxf(Vrr * Vii - Vri * Vri, EPSV), DELTA_MAX);
    const float s   = sqrtf(delta);
    const float t   = sqrtf(tau + 2.0f * s);
    const float rst = 1.0f / (s * t);
    const float Urr = (s + Vii) * rst;
    const float Uii = (s + Vrr) * rst;
    const float Uri = -Vri * rst;

    float wrr, wri, wii, br, bi;
    if (flags[1]) {
        wrr = ((const float*)Wrr_p)[j];  wri = ((const float*)Wri_p)[j];
        wii = ((const float*)Wii_p)[j];
        br  = ((const float*)Br_p)[j];   bi  = ((const float*)Bi_p)[j];
    } else {
        wrr = bf1(((const uint16_t*)Wrr_p)[j]);  wri = bf1(((const uint16_t*)Wri_p)[j]);
        wii = bf1(((const uint16_t*)Wii_p)[j]);
        br  = bf1(((const uint16_t*)Br_p)[j]);   bi  = bf1(((const uint16_t*)Bi_p)[j]);
    }
    const float Zrr = wrr * Urr + wri * Uri;
    const float Zri = wrr * Uri + wri * Uii;
    const float Zir = wri * Urr + wii * Uri;
    const float Zii = wri * Uri + wii * Uii;
    coef[0*NCOLS+j] = Zrr;
    coef[1*NCOLS+j] = Zri;
    coef[2*NCOLS+j] = Zir;
    coef[3*NCOLS+j] = Zii;
    coef[4*NCOLS+j] = br - Zrr * Mr - Zri * Mi;
    coef[5*NCOLS+j] = bi - Zir * Mr - Zii * Mi;
}

// ---------------- Pass 3: apply (column-stationary, coeffs in regs) ----------
// The round-1-bench (533 us) apply: grid 2056 x block 256, T = 526336 =
// 2048*257 bijection, flat-contiguous stream, NT stores. NT targets use
// ext_vector_type pointers (bit-identical to float4/uint4) because
// __builtin_nontemporal_store rejects HIP_vector_type — round-6 compile fix.
__global__ __launch_bounds__(256) void apply_kernel(
    const void* __restrict__ xr_p, const void* __restrict__ xi_p,
    const float* __restrict__ coef, const int* __restrict__ flags,
    void* __restrict__ out_p)
{
    const int tid = blockIdx.x * 256 + threadIdx.x;
    const int c  = tid % NG;
    const int r0 = tid / NG;            // [0,2048)
    const int col = c * 8;

    float Z[6][8];
    #pragma unroll
    for (int t = 0; t < 6; ++t) {
        const float4 lo = *(const float4*)(coef + t*NCOLS + col);
        const float4 hi = *(const float4*)(coef + t*NCOLS + col + 4);
        Z[t][0]=lo.x; Z[t][1]=lo.y; Z[t][2]=lo.z; Z[t][3]=lo.w;
        Z[t][4]=hi.x; Z[t][5]=hi.y; Z[t][6]=hi.z; Z[t][7]=hi.w;
    }

    if (flags[0]) {
        // -------- fp32 path --------
        const float4* xr4 = (const float4*)xr_p;
        const float4* xi4 = (const float4*)xi_p;
        f32x4v* yr4 = (f32x4v*)out_p;
        f32x4v* yi4 = yr4 + (size_t)NROWS * 514;   // yi after N*C*F floats
        #pragma unroll 2
        for (int k = 0; k < 8; ++k) {
            const size_t g = (size_t)(r0 + (k << 11)) * 514 + 2 * c;
            const float4 a0 = xr4[g], a1 = xr4[g + 1];
            const float4 b0 = xi4[g], b1 = xi4[g + 1];
            const float xrv[8] = {a0.x,a0.y,a0.z,a0.w,a1.x,a1.y,a1.z,a1.w};
            const float xiv[8] = {b0.x,b0.y,b0.z,b0.w,b1.x,b1.y,b1.z,b1.w};
            float yrv[8], yiv[8];
            #pragma unroll
            for (int j = 0; j < 8; ++j) {
                yrv[j] = Z[0][j]*xrv[j] + Z[1][j]*xiv[j] + Z[4][j];
                yiv[j] = Z[2][j]*xrv[j] + Z[3][j]*xiv[j] + Z[5][j];
            }
            const f32x4v s0 = {yrv[0], yrv[1], yrv[2], yrv[3]};
            const f32x4v s1 = {yrv[4], yrv[5], yrv[6], yrv[7]};
            const f32x4v t0 = {yiv[0], yiv[1], yiv[2], yiv[3]};
            const f32x4v t1 = {yiv[4], yiv[5], yiv[6], yiv[7]};
            __builtin_nontemporal_store(s0, yr4 + g);
            __builtin_nontemporal_store(s1, yr4 + g + 1);
            __builtin_nontemporal_store(t0, yi4 + g);
            __builtin_nontemporal_store(t1, yi4 + g + 1);
        }
    } else {
        // -------- bf16 path --------
        const uint4* xr4 = (const uint4*)xr_p;
        const uint4* xi4 = (const uint4*)xi_p;
        u32x4v* yr4 = (u32x4v*)out_p;
        u32x4v* yi4 = yr4 + (size_t)NROWS * NG;     // yi after N*C*F bf16
        #pragma unroll 2
        for (int k = 0; k < 8; ++k) {
            const size_t g = (size_t)(r0 + (k << 11)) * NG + c;
            const uint4 a = xr4[g];
            const uint4 b = xi4[g];
            const uint32_t au[4] = {a.x, a.y, a.z, a.w};
            const uint32_t bu[4] = {b.x, b.y, b.z, b.w};
            uint32_t ou[4], pu[4];
            #pragma unroll
            for (int j = 0; j < 4; ++j) {
                const int e0 = 2*j, e1 = 2*j + 1;
                const float xr0 = bf_lo(au[j]), xr1 = bf_hi(au[j]);
                const float xi0 = bf_lo(bu[j]), xi1 = bf_hi(bu[j]);
                const float yr0 = Z[0][e0]*xr0 + Z[1][e0]*xi0 + Z[4][e0];
                const float yi0 = Z[2][e0]*xr0 + Z[3][e0]*xi0 + Z[5][e0];
                const float yr1 = Z[0][e1]*xr1 + Z[1][e1]*xi1 + Z[4][e1];
                const float yi1 = Z[2][e1]*xr1 + Z[3][e1]*xi1 + Z[5][e1];
                ou[j] = bf16pair(yr0, yr1);
                pu[j] = bf16pair(yi0, yi1);
            }
            const u32x4v o = {ou[0], ou[1], ou[2], ou[3]};
            const u32x4v p = {pu[0], pu[1], pu[2], pu[3]};
            __builtin_nontemporal_store(o, yr4 + g);
            __builtin_nontemporal_store(p, yi4 + g);
        }
    }
}

extern "C" void kernel_launch(void* const* d_in, const int* in_sizes, int n_in,
                              void* d_out, int out_size, void* d_ws, size_t ws_size,
                              hipStream_t stream)
{
    const void* xr_p = d_in[0];
    const void* xi_p = d_in[1];
    const void* Wrr  = d_in[2];
    const void* Wri  = d_in[3];
    const void* Wii  = d_in[4];
    const void* Br   = d_in[5];
    const void* Bi   = d_in[6];

    float* sums  = (float*)d_ws;             // 5 * 2056 f32
    float* coef  = sums + 5 * NCOLS;         // 6 * 2056 f32
    int*   flags = (int*)(coef + 6 * NCOLS); // 2 ints

    detect_kernel<<<1, 512, 0, stream>>>((const uint32_t*)xr_p, (const uint32_t*)Wrr, flags);
    (void)hipMemsetAsync(sums, 0, 5 * NCOLS * sizeof(float), stream);
    stats_kernel<<<dim3(SR, 33), 256, 0, stream>>>(xr_p, xi_p, flags, sums);
    coef_kernel<<<(NCOLS + 255) / 256, 256, 0, stream>>>(sums, Wrr, Wri, Wii, Br, Bi, flags, coef);
    apply_kernel<<<2056, 256, 0, stream>>>(xr_p, xi_p, coef, flags, d_out);
}

// Round 8
// 534.792 us; speedup vs baseline: 1.2350x; 1.0239x over previous
//
#include <hip/hip_runtime.h>
#include <stdint.h>

// Problem: ComplexDepthwiseBatchNorm  N=16384, C=8, F=257
// Layout: x[N][C*F] row-major; NCOLS = 2056 columns per row.
// Dtype of x / W / out is detected ON DEVICE (bf16 vs fp32) — see detect_kernel.
#define NROWS   16384
#define NCOLS   2056
#define NG      257          // groups of 8 elements per row (2056/8)
#define EPSV    1e-6f
#define DELTA_MAX 1e8f
#define SR      64           // row slices for stats (NROWS/SR = 256 rows/slice)

typedef float    f32x4v __attribute__((ext_vector_type(4)));
typedef float    f32x8v __attribute__((ext_vector_type(8)));
typedef uint32_t u32x4v __attribute__((ext_vector_type(4)));

__device__ __forceinline__ float bf_lo(uint32_t u) {
    return __builtin_bit_cast(float, u << 16);
}
__device__ __forceinline__ float bf_hi(uint32_t u) {
    return __builtin_bit_cast(float, u & 0xffff0000u);
}
__device__ __forceinline__ float bf1(uint16_t u) {
    return __builtin_bit_cast(float, (uint32_t)u << 16);
}
// round-to-nearest-even bf16 pair pack: lo -> bits[15:0], hi -> bits[31:16]
__device__ __forceinline__ uint32_t bf16pair(float lo, float hi) {
    uint32_t ul = __builtin_bit_cast(uint32_t, lo);
    uint32_t uh = __builtin_bit_cast(uint32_t, hi);
    ul = (ul + 0x7fffu + ((ul >> 16) & 1u)) >> 16;
    uh = (uh + 0x7fffu + ((uh >> 16) & 1u)) & 0xffff0000u;
    return ul | uh;
}

// ---------------- Pass 0: dtype detection ----------------
// flags[0]=1 iff x is fp32; flags[1]=1 iff W/B are fp32.
__global__ __launch_bounds__(512) void detect_kernel(
    const uint32_t* __restrict__ xr_u, const uint32_t* __restrict__ wrr_u,
    int* __restrict__ flags)
{
    __shared__ int cnt[2];
    if (threadIdx.x < 2) cnt[threadIdx.x] = 0;
    __syncthreads();
    const int part = threadIdx.x >> 8;                    // 0: x, 1: Wrr
    const uint32_t u = part ? wrr_u[threadIdx.x & 255] : xr_u[threadIdx.x & 255];
    const uint32_t e = (u >> 7) & 0xFFu;
    const int ok = (e >= 100u && e <= 131u) ? 1 : 0;
    atomicAdd(&cnt[part], ok);
    __syncthreads();
    if (threadIdx.x == 0) {
        flags[0] = (cnt[0] < 128) ? 1 : 0;
        flags[1] = (cnt[1] < 128) ? 1 : 0;
    }
}

// ---------------- Pass 1: per-column sums (tile-stationary, NT loads) -------
// Structure identical to the proven round-1/7 config (grid dim3(SR,33),
// block 256; shfl_xor over lane bits 3..5 -> LDS combine -> 320 atomics),
// register f32x8 accumulators, __launch_bounds__(256,4).
// ONE change this round: x loads are NON-TEMPORAL. Theory: the ~140 us /
// ~1 TB/s stats wall survived concurrency x8, three access patterns, and
// register promotion — every demand-side cause falsified. Sole survivor:
// COLD-READ L3 ALLOCATION RATE. Evidence: the 6.5 TB/s harness fill does NT
// writes (no allocate); apply reads x L3-warm at ~4 TB/s; only stats reads
// cold, and 135 MB of line allocations / 140 us ~= 1 TB/s. NT loads bypass
// allocation -> should read at HBM peak. x is then uncached, so apply also
// NT-loads x (it is never read again afterwards — semantically correct).
__global__ __launch_bounds__(256, 4) void stats_kernel(
    const void* __restrict__ xr_p, const void* __restrict__ xi_p,
    const int* __restrict__ flags, float* __restrict__ sums)
{
    const int rs = blockIdx.x;          // 0..SR-1
    const int ct = blockIdx.y;          // 0..32
    const int t  = threadIdx.x;
    const int rbase = rs * (NROWS / SR);   // 256 rows per slice

    f32x8v sr  = {0.f,0.f,0.f,0.f,0.f,0.f,0.f,0.f};
    f32x8v si  = sr, srr = sr, sri = sr, sii = sr;

    const bool isfp32 = (flags[0] != 0);

    if (ct < 32) {
        const int grp = ct * 8 + (t & 7);
        const int rl  = t >> 3;             // 0..31
        if (!isfp32) {
            const u32x4v* xr4 = (const u32x4v*)xr_p;
            const u32x4v* xi4 = (const u32x4v*)xi_p;
            #pragma unroll 2
            for (int k = 0; k < 8; ++k) {
                const size_t g = (size_t)(rbase + rl + 32*k) * NG + grp;
                const u32x4v a = __builtin_nontemporal_load(xr4 + g);
                const u32x4v b = __builtin_nontemporal_load(xi4 + g);
                #pragma unroll
                for (int j = 0; j < 4; ++j) {
                    const float r0 = bf_lo(a[j]), r1 = bf_hi(a[j]);
                    const float i0 = bf_lo(b[j]), i1 = bf_hi(b[j]);
                    sr [2*j]   += r0;       si [2*j]   += i0;
                    srr[2*j]   += r0*r0;    sri[2*j]   += r0*i0;    sii[2*j]   += i0*i0;
                    sr [2*j+1] += r1;       si [2*j+1] += i1;
                    srr[2*j+1] += r1*r1;    sri[2*j+1] += r1*i1;    sii[2*j+1] += i1*i1;
                }
            }
        } else {
            const f32x4v* xr4 = (const f32x4v*)xr_p;
            const f32x4v* xi4 = (const f32x4v*)xi_p;
            #pragma unroll 2
            for (int k = 0; k < 8; ++k) {
                const size_t g = (size_t)(rbase + rl + 32*k) * 514 + 2*grp;
                const f32x4v a0 = __builtin_nontemporal_load(xr4 + g);
                const f32x4v a1 = __builtin_nontemporal_load(xr4 + g + 1);
                const f32x4v b0 = __builtin_nontemporal_load(xi4 + g);
                const f32x4v b1 = __builtin_nontemporal_load(xi4 + g + 1);
                #pragma unroll
                for (int j = 0; j < 4; ++j) {
                    sr [j] += a0[j];        si [j] += b0[j];
                    srr[j] += a0[j]*a0[j];  sri[j] += a0[j]*b0[j];  sii[j] += b0[j]*b0[j];
                    sr [4+j] += a1[j];        si [4+j] += b1[j];
                    srr[4+j] += a1[j]*a1[j];  sri[4+j] += a1[j]*b1[j];
                    sii[4+j] += b1[j]*b1[j];
                }
            }
        }
        // reduce over the 8 row-lanes sharing this group (lane bits 3..5)
        #pragma unroll
        for (int m = 8; m <= 32; m <<= 1) {
            #pragma unroll
            for (int e = 0; e < 8; ++e) {
                sr [e] += __shfl_xor(sr [e], m, 64);
                si [e] += __shfl_xor(si [e], m, 64);
                srr[e] += __shfl_xor(srr[e], m, 64);
                sri[e] += __shfl_xor(sri[e], m, 64);
                sii[e] += __shfl_xor(sii[e], m, 64);
            }
        }
    } else {
        // leftover group 256 (columns 2048..2055): one row per thread
        if (!isfp32) {
            const u32x4v* xr4 = (const u32x4v*)xr_p;
            const u32x4v* xi4 = (const u32x4v*)xi_p;
            const size_t g = (size_t)(rbase + t) * NG + 256;
            const u32x4v a = __builtin_nontemporal_load(xr4 + g);
            const u32x4v b = __builtin_nontemporal_load(xi4 + g);
            #pragma unroll
            for (int j = 0; j < 4; ++j) {
                const float r0 = bf_lo(a[j]), r1 = bf_hi(a[j]);
                const float i0 = bf_lo(b[j]), i1 = bf_hi(b[j]);
                sr [2*j]   += r0;       si [2*j]   += i0;
                srr[2*j]   += r0*r0;    sri[2*j]   += r0*i0;    sii[2*j]   += i0*i0;
                sr [2*j+1] += r1;       si [2*j+1] += i1;
                srr[2*j+1] += r1*r1;    sri[2*j+1] += r1*i1;    sii[2*j+1] += i1*i1;
            }
        } else {
            const f32x4v* xr4 = (const f32x4v*)xr_p;
            const f32x4v* xi4 = (const f32x4v*)xi_p;
            const size_t g = (size_t)(rbase + t) * 514 + 512;
            const f32x4v a0 = __builtin_nontemporal_load(xr4 + g);
            const f32x4v a1 = __builtin_nontemporal_load(xr4 + g + 1);
            const f32x4v b0 = __builtin_nontemporal_load(xi4 + g);
            const f32x4v b1 = __builtin_nontemporal_load(xi4 + g + 1);
            #pragma unroll
            for (int j = 0; j < 4; ++j) {
                sr [j] += a0[j];        si [j] += b0[j];
                srr[j] += a0[j]*a0[j];  sri[j] += a0[j]*b0[j];  sii[j] += b0[j]*b0[j];
                sr [4+j] += a1[j];        si [4+j] += b1[j];
                srr[4+j] += a1[j]*a1[j];  sri[4+j] += a1[j]*b1[j];
                sii[4+j] += b1[j]*b1[j];
            }
        }
        // full 64-lane reduction
        #pragma unroll
        for (int m = 1; m <= 32; m <<= 1) {
            #pragma unroll
            for (int e = 0; e < 8; ++e) {
                sr [e] += __shfl_xor(sr [e], m, 64);
                si [e] += __shfl_xor(si [e], m, 64);
                srr[e] += __shfl_xor(srr[e], m, 64);
                sri[e] += __shfl_xor(sri[e], m, 64);
                sii[e] += __shfl_xor(sii[e], m, 64);
            }
        }
    }

    // cross-wave combine: per-wave representatives -> LDS -> sum 4 -> atomic
    __shared__ float red[4][320];
    const int wv = t >> 6, ln = t & 63;
    if (ct < 32) {
        if (ln < 8) {
            #pragma unroll
            for (int e = 0; e < 8; ++e) {
                red[wv][ln*40 + 0*8 + e] = sr [e];
                red[wv][ln*40 + 1*8 + e] = si [e];
                red[wv][ln*40 + 2*8 + e] = srr[e];
                red[wv][ln*40 + 3*8 + e] = sri[e];
                red[wv][ln*40 + 4*8 + e] = sii[e];
            }
        }
    } else {
        if (ln == 0) {
            #pragma unroll
            for (int e = 0; e < 8; ++e) {
                red[wv][0*8 + e] = sr [e];
                red[wv][1*8 + e] = si [e];
                red[wv][2*8 + e] = srr[e];
                red[wv][3*8 + e] = sri[e];
                red[wv][4*8 + e] = sii[e];
            }
        }
    }
    __syncthreads();
    const int nvals = (ct < 32) ? 320 : 40;
    for (int idx = t; idx < nvals; idx += 256) {
        const float v = red[0][idx] + red[1][idx] + red[2][idx] + red[3][idx];
        const int gi  = idx / 40;
        const int j   = idx - gi * 40;          // stat*8 + colj
        const int col = (ct * 8 + gi) * 8 + (j & 7);
        atomicAdd(&sums[(j >> 3) * NCOLS + col], v);
    }
}

// ---------------- Pass 2: sums -> per-column coefficients ----------------
__global__ __launch_bounds__(256) void coef_kernel(
    const float* __restrict__ sums,
    const void* __restrict__ Wrr_p, const void* __restrict__ Wri_p,
    const void* __restrict__ Wii_p, const void* __restrict__ Br_p,
    const void* __restrict__ Bi_p,
    const int* __restrict__ flags, float* __restrict__ coef)
{
    const int j = blockIdx.x * 256 + threadIdx.x;
    if (j >= NCOLS) return;
    const float invN = 1.0f / (float)NROWS;
    const float Mr  = sums[0*NCOLS+j] * invN;
    const float Mi  = sums[1*NCOLS+j] * invN;
    const float Vrr = sums[2*NCOLS+j] * invN - Mr * Mr;
    const float Vri = sums[3*NCOLS+j] * invN - Mr * Mi;
    const float Vii = sums[4*NCOLS+j] * invN - Mi * Mi;
    const float tau   = Vrr + Vii;
    const float delta = fminf(fmaxf(Vrr * Vii - Vri * Vri, EPSV), DELTA_MAX);
    const float s   = sqrtf(delta);
    const float t   = sqrtf(tau + 2.0f * s);
    const float rst = 1.0f / (s * t);
    const float Urr = (s + Vii) * rst;
    const float Uii = (s + Vrr) * rst;
    const float Uri = -Vri * rst;

    float wrr, wri, wii, br, bi;
    if (flags[1]) {
        wrr = ((const float*)Wrr_p)[j];  wri = ((const float*)Wri_p)[j];
        wii = ((const float*)Wii_p)[j];
        br  = ((const float*)Br_p)[j];   bi  = ((const float*)Bi_p)[j];
    } else {
        wrr = bf1(((const uint16_t*)Wrr_p)[j]);  wri = bf1(((const uint16_t*)Wri_p)[j]);
        wii = bf1(((const uint16_t*)Wii_p)[j]);
        br  = bf1(((const uint16_t*)Br_p)[j]);   bi  = bf1(((const uint16_t*)Bi_p)[j]);
    }
    const float Zrr = wrr * Urr + wri * Uri;
    const float Zri = wrr * Uri + wri * Uii;
    const float Zir = wri * Urr + wii * Uri;
    const float Zii = wri * Uri + wii * Uii;
    coef[0*NCOLS+j] = Zrr;
    coef[1*NCOLS+j] = Zri;
    coef[2*NCOLS+j] = Zir;
    coef[3*NCOLS+j] = Zii;
    coef[4*NCOLS+j] = br - Zrr * Mr - Zri * Mi;
    coef[5*NCOLS+j] = bi - Zir * Mr - Zii * Mi;
}

// ---------------- Pass 3: apply (column-stationary, NT loads + NT stores) ---
// grid 2056 x block 256, T = 526336 = 2048*257 bijection, flat-contiguous.
// x is NT-loaded (it is uncached now that stats NT-loads it, and it is never
// read again after this kernel); y is NT-stored (never re-read).
__global__ __launch_bounds__(256) void apply_kernel(
    const void* __restrict__ xr_p, const void* __restrict__ xi_p,
    const float* __restrict__ coef, const int* __restrict__ flags,
    void* __restrict__ out_p)
{
    const int tid = blockIdx.x * 256 + threadIdx.x;
    const int c  = tid % NG;
    const int r0 = tid / NG;            // [0,2048)
    const int col = c * 8;

    float Z[6][8];
    #pragma unroll
    for (int t = 0; t < 6; ++t) {
        const float4 lo = *(const float4*)(coef + t*NCOLS + col);
        const float4 hi = *(const float4*)(coef + t*NCOLS + col + 4);
        Z[t][0]=lo.x; Z[t][1]=lo.y; Z[t][2]=lo.z; Z[t][3]=lo.w;
        Z[t][4]=hi.x; Z[t][5]=hi.y; Z[t][6]=hi.z; Z[t][7]=hi.w;
    }

    if (flags[0]) {
        // -------- fp32 path --------
        const f32x4v* xr4 = (const f32x4v*)xr_p;
        const f32x4v* xi4 = (const f32x4v*)xi_p;
        f32x4v* yr4 = (f32x4v*)out_p;
        f32x4v* yi4 = yr4 + (size_t)NROWS * 514;   // yi after N*C*F floats
        #pragma unroll 2
        for (int k = 0; k < 8; ++k) {
            const size_t g = (size_t)(r0 + (k << 11)) * 514 + 2 * c;
            const f32x4v a0 = __builtin_nontemporal_load(xr4 + g);
            const f32x4v a1 = __builtin_nontemporal_load(xr4 + g + 1);
            const f32x4v b0 = __builtin_nontemporal_load(xi4 + g);
            const f32x4v b1 = __builtin_nontemporal_load(xi4 + g + 1);
            const float xrv[8] = {a0[0],a0[1],a0[2],a0[3],a1[0],a1[1],a1[2],a1[3]};
            const float xiv[8] = {b0[0],b0[1],b0[2],b0[3],b1[0],b1[1],b1[2],b1[3]};
            float yrv[8], yiv[8];
            #pragma unroll
            for (int j = 0; j < 8; ++j) {
                yrv[j] = Z[0][j]*xrv[j] + Z[1][j]*xiv[j] + Z[4][j];
                yiv[j] = Z[2][j]*xrv[j] + Z[3][j]*xiv[j] + Z[5][j];
            }
            const f32x4v s0 = {yrv[0], yrv[1], yrv[2], yrv[3]};
            const f32x4v s1 = {yrv[4], yrv[5], yrv[6], yrv[7]};
            const f32x4v t0 = {yiv[0], yiv[1], yiv[2], yiv[3]};
            const f32x4v t1 = {yiv[4], yiv[5], yiv[6], yiv[7]};
            __builtin_nontemporal_store(s0, yr4 + g);
            __builtin_nontemporal_store(s1, yr4 + g + 1);
            __builtin_nontemporal_store(t0, yi4 + g);
            __builtin_nontemporal_store(t1, yi4 + g + 1);
        }
    } else {
        // -------- bf16 path --------
        const u32x4v* xr4 = (const u32x4v*)xr_p;
        const u32x4v* xi4 = (const u32x4v*)xi_p;
        u32x4v* yr4 = (u32x4v*)out_p;
        u32x4v* yi4 = yr4 + (size_t)NROWS * NG;     // yi after N*C*F bf16
        #pragma unroll 2
        for (int k = 0; k < 8; ++k) {
            const size_t g = (size_t)(r0 + (k << 11)) * NG + c;
            const u32x4v a = __builtin_nontemporal_load(xr4 + g);
            const u32x4v b = __builtin_nontemporal_load(xi4 + g);
            uint32_t ou[4], pu[4];
            #pragma unroll
            for (int j = 0; j < 4; ++j) {
                const int e0 = 2*j, e1 = 2*j + 1;
                const float xr0 = bf_lo(a[j]), xr1 = bf_hi(a[j]);
                const float xi0 = bf_lo(b[j]), xi1 = bf_hi(b[j]);
                const float yr0 = Z[0][e0]*xr0 + Z[1][e0]*xi0 + Z[4][e0];
                const float yi0 = Z[2][e0]*xr0 + Z[3][e0]*xi0 + Z[5][e0];
                const float yr1 = Z[0][e1]*xr1 + Z[1][e1]*xi1 + Z[4][e1];
                const float yi1 = Z[2][e1]*xr1 + Z[3][e1]*xi1 + Z[5][e1];
                ou[j] = bf16pair(yr0, yr1);
                pu[j] = bf16pair(yi0, yi1);
            }
            const u32x4v o = {ou[0], ou[1], ou[2], ou[3]};
            const u32x4v p = {pu[0], pu[1], pu[2], pu[3]};
            __builtin_nontemporal_store(o, yr4 + g);
            __builtin_nontemporal_store(p, yi4 + g);
        }
    }
}

extern "C" void kernel_launch(void* const* d_in, const int* in_sizes, int n_in,
                              void* d_out, int out_size, void* d_ws, size_t ws_size,
                              hipStream_t stream)
{
    const void* xr_p = d_in[0];
    const void* xi_p = d_in[1];
    const void* Wrr  = d_in[2];
    const void* Wri  = d_in[3];
    const void* Wii  = d_in[4];
    const void* Br   = d_in[5];
    const void* Bi   = d_in[6];

    float* sums  = (float*)d_ws;             // 5 * 2056 f32
    float* coef  = sums + 5 * NCOLS;         // 6 * 2056 f32
    int*   flags = (int*)(coef + 6 * NCOLS); // 2 ints

    detect_kernel<<<1, 512, 0, stream>>>((const uint32_t*)xr_p, (const uint32_t*)Wrr, flags);
    (void)hipMemsetAsync(sums, 0, 5 * NCOLS * sizeof(float), stream);
    stats_kernel<<<dim3(SR, 33), 256, 0, stream>>>(xr_p, xi_p, flags, sums);
    coef_kernel<<<(NCOLS + 255) / 256, 256, 0, stream>>>(sums, Wrr, Wri, Wii, Br, Bi, flags, coef);
    apply_kernel<<<2056, 256, 0, stream>>>(xr_p, xi_p, coef, flags, d_out);
}